// Round 16
// baseline (86.234 us; speedup 1.0000x reference)
//
#include <hip/hip_runtime.h>
#include <hip/hip_bf16.h>

#define S_LEN 2048
#define NH 16
#define HD 64

typedef __attribute__((ext_vector_type(8))) __bf16 bf16x8;
typedef __attribute__((ext_vector_type(16))) float f32x16;

// 0.125 (1/sqrt(64)) * log2(e): folded into Q so softmax uses exp2 directly
#define QSCALE 0.1803368801111204f

static __device__ __forceinline__ ushort f2bf(float f) {
    unsigned int u = __float_as_uint(f);
    u += 0x7fffu + ((u >> 16) & 1u);
    return (ushort)(u >> 16);
}

static __device__ __forceinline__ unsigned cvtpk_bf16(float lo, float hi) {
    unsigned r;
    asm("v_cvt_pk_bf16_f32 %0, %1, %2" : "=v"(r) : "v"(lo), "v"(hi));
    return r;
}
static __device__ __forceinline__ float exp2_fast(float x) {
    float r;
    asm("v_exp_f32 %0, %1" : "=v"(r) : "v"(x));
    return r;
}

// ---------------------------------------------------------------------------
// K prepass: [B,S,H,D] f32 -> frag-order bf16.  (r2/r7-proven, verbatim)
// ---------------------------------------------------------------------------
__global__ __launch_bounds__(256) void prep_k_kernel(const float* __restrict__ in,
                                                     ushort* __restrict__ out) {
    unsigned t = blockIdx.x * 256u + threadIdx.x;   // 524288 total
    unsigned o = t & 7u;            // d-octet
    unsigned s = (t >> 3) & 2047u;
    unsigned bh = t >> 14;
    unsigned b = bh >> 4, h = bh & 15u;
    const float* src = in + (((size_t)(b * S_LEN) + s) * NH + h) * HD + o * 8;
    float4 x = *(const float4*)src;
    float4 y = *(const float4*)(src + 4);
    union { ushort u[8]; uint4 q; } fu;
    fu.u[0] = f2bf(x.x); fu.u[1] = f2bf(x.y); fu.u[2] = f2bf(x.z); fu.u[3] = f2bf(x.w);
    fu.u[4] = f2bf(y.x); fu.u[5] = f2bf(y.y); fu.u[6] = f2bf(y.z); fu.u[7] = f2bf(y.w);
    unsigned kt = s >> 6, kh = (s >> 5) & 1u, kl = s & 31u;
    unsigned dchunk = o >> 1, ho = o & 1u;
    size_t ci = (((size_t)(bh * 32u + kt) * 2u + kh) * 4u + dchunk) * 64u + kl + 32u * ho;
    *(uint4*)(out + ci * 8u) = fu.q;
}

// ---------------------------------------------------------------------------
// V prepass: [B,S,H,D] f32 -> frag-order V^T bf16.  (r2/r7-proven, verbatim)
// ---------------------------------------------------------------------------
__global__ __launch_bounds__(256) void prep_v_kernel(const float* __restrict__ in,
                                                     ushort* __restrict__ out) {
    __shared__ float T[64][68];
    const unsigned tid = threadIdx.x;
    const unsigned kt = blockIdx.x, bh = blockIdx.y;
    const unsigned b = bh >> 4, h = bh & 15u;
#pragma unroll
    for (int i = 0; i < 4; ++i) {
        unsigned idx = tid + i * 256u;
        unsigned sl = idx >> 4, d4 = (idx & 15u) * 4u;
        float4 v = *(const float4*)(in + (((size_t)(b * S_LEN) + kt * 64u + sl) * NH + h) * HD + d4);
        *(float4*)&T[sl][d4] = v;
    }
    __syncthreads();
#pragma unroll
    for (int it = 0; it < 2; ++it) {
        unsigned ct = tid + it * 256u;
        unsigned l = ct & 63u, sub = ct >> 6;
        unsigned nt = sub & 1u, c = (sub >> 1) & 1u, kh = sub >> 2;
        unsigned d = (l & 31u) + 32u * nt;
        unsigned kb = kh * 32u + c * 16u + (l >> 5) * 8u;
        union { ushort u[8]; uint4 q; } fu;
#pragma unroll
        for (int j = 0; j < 8; ++j) fu.u[j] = f2bf(T[kb + j][d]);
        *(uint4*)(out + ((size_t)(bh * 32u + kt) * 8u + sub) * 512u + l * 8u) = fu.q;
    }
}

// ---------------------------------------------------------------------------
// Flash attention r15 (RERUN -- container died before bench): BARRIER-FREE
// main loop. All K/V/mask loads are register-direct from frag-order ws (one
// coalesced global_load_dwordx4 per fragment at base+lane*16) -- no LDS
// staging, no s_barrier, no manual vmcnt in the loop. Waves slip freely;
// compiler inserts exact per-use vmcnt; 4 waves/SIMD TLP hides L2 latency
// (m114 mechanism, previously blocked by the r10 per-tile barrier convoy).
// Inner algebra = r10 verbatim (scalar lsum, no ones-MFMA, no kh-pipeline --
// r14 proved those regress). 8 waves (4 qsub x 2 kgrp), KBLK=64;
// LDS = 34KB combine overlay only.
// C-init BANNED; counted-vmcnt BANNED; launch_bounds >= 6 BANNED.
// ---------------------------------------------------------------------------
struct CombMem {
    float ob[4][32][64];    // 32 KB
    float lsb[4][64];
    float rls[4][32];
};

__global__ __launch_bounds__(512, 4) void attn_kernel(const float* __restrict__ Qp,
                                                      const ushort* __restrict__ Kws,
                                                      const ushort* __restrict__ Vws,
                                                      const int* __restrict__ maskp,
                                                      float* __restrict__ outp) {
    __shared__ __align__(16) CombMem sm;

    const unsigned tid = threadIdx.x;
    const unsigned wid = tid >> 6;
    const unsigned lane = tid & 63u;
    const unsigned l31 = lane & 31u;
    const unsigned hi = lane >> 5;
    const unsigned qsub = wid & 3u;
    const unsigned kgrp = wid >> 2;

    const unsigned bh = blockIdx.y;
    const unsigned b = bh >> 4, h = bh & 15u;
    const unsigned q0 = blockIdx.x * 128u + qsub * 32u;

    // Q fragments (B-operand of swapped QK^T): lane holds Q[q0+l31][16dc+8hi+j]
    bf16x8 qf[4];
    {
        const float* qb = Qp + (((size_t)(b * S_LEN) + q0 + l31) * NH + h) * HD + hi * 8u;
#pragma unroll
        for (int dc = 0; dc < 4; ++dc) {
            float4 x = *(const float4*)(qb + dc * 16);
            float4 y = *(const float4*)(qb + dc * 16 + 4);
            union { ushort u[8]; bf16x8 v; } fu;
            fu.u[0] = f2bf(x.x * QSCALE); fu.u[1] = f2bf(x.y * QSCALE);
            fu.u[2] = f2bf(x.z * QSCALE); fu.u[3] = f2bf(x.w * QSCALE);
            fu.u[4] = f2bf(y.x * QSCALE); fu.u[5] = f2bf(y.y * QSCALE);
            fu.u[6] = f2bf(y.z * QSCALE); fu.u[7] = f2bf(y.w * QSCALE);
            qf[dc] = fu.v;
        }
    }

    f32x16 oacc0 = {0,0,0,0,0,0,0,0,0,0,0,0,0,0,0,0};
    f32x16 oacc1 = {0,0,0,0,0,0,0,0,0,0,0,0,0,0,0,0};
    float ls0 = 0.f, ls1 = 0.f, ls2 = 0.f, ls3 = 0.f;

    // register-direct per-lane bases (ushort units); kgrp covers 16 KBLK=64
    // tiles at ushort-stride 4096
    const ushort* kg = Kws + (size_t)bh * 131072u + (size_t)kgrp * 65536u + lane * 8u;
    const ushort* vg = Vws + (size_t)bh * 131072u + (size_t)kgrp * 65536u + lane * 8u;
    const int* mg = maskp + (size_t)b * S_LEN + kgrp * 1024u;

#pragma unroll 2
    for (int t = 0; t < 16; ++t) {
        const ushort* kt_p = kg + (unsigned)t * 4096u;
        const ushort* vt_p = vg + (unsigned)t * 4096u;
        const int*    mt   = mg + t * 64;

#pragma unroll
        for (int kh = 0; kh < 2; ++kh) {
            bf16x8 kf[4];
#pragma unroll
            for (int dc = 0; dc < 4; ++dc)
                kf[dc] = *(const bf16x8*)(kt_p + (kh * 4 + dc) * 512u);

            f32x16 s = {0,0,0,0,0,0,0,0,0,0,0,0,0,0,0,0};
            __builtin_amdgcn_s_setprio(1);
#pragma unroll
            for (int dc = 0; dc < 4; ++dc)
                s = __builtin_amdgcn_mfma_f32_32x32x16_bf16(kf[dc], qf[dc], s, 0, 0, 0);
            __builtin_amdgcn_s_setprio(0);

            // mask post-MFMA (r7-proven): masked keys -> exp2(-1e30) = 0
            float p[16];
#pragma unroll
            for (int r1 = 0; r1 < 4; ++r1) {
                int4 mv = *(const int4*)(mt + kh * 32 + r1 * 8 + hi * 4);
                p[r1 * 4 + 0] = exp2_fast(mv.x ? s[r1 * 4 + 0] : -1e30f);
                p[r1 * 4 + 1] = exp2_fast(mv.y ? s[r1 * 4 + 1] : -1e30f);
                p[r1 * 4 + 2] = exp2_fast(mv.z ? s[r1 * 4 + 2] : -1e30f);
                p[r1 * 4 + 3] = exp2_fast(mv.w ? s[r1 * 4 + 3] : -1e30f);
                ls0 += p[r1 * 4 + 0]; ls1 += p[r1 * 4 + 1];
                ls2 += p[r1 * 4 + 2]; ls3 += p[r1 * 4 + 3];
            }

            // pack P -> PV A-frags: cvt_pk + permlane32_swap (r9/r10-proven)
#pragma unroll
            for (int c = 0; c < 2; ++c) {
                unsigned a0 = cvtpk_bf16(p[8 * c + 0], p[8 * c + 1]);
                unsigned a1 = cvtpk_bf16(p[8 * c + 2], p[8 * c + 3]);
                unsigned b0 = cvtpk_bf16(p[8 * c + 4], p[8 * c + 5]);
                unsigned b1 = cvtpk_bf16(p[8 * c + 6], p[8 * c + 7]);
                asm("v_permlane32_swap_b32 %0, %1" : "+v"(a0), "+v"(b0));
                asm("v_permlane32_swap_b32 %0, %1" : "+v"(a1), "+v"(b1));
                union { unsigned w[4]; bf16x8 v; } pa;
                pa.w[0] = a0; pa.w[1] = a1; pa.w[2] = b0; pa.w[3] = b1;
                bf16x8 vf0 = *(const bf16x8*)(vt_p + ((kh * 2 + c) * 2 + 0) * 512u);
                bf16x8 vf1 = *(const bf16x8*)(vt_p + ((kh * 2 + c) * 2 + 1) * 512u);
                __builtin_amdgcn_s_setprio(1);
                oacc0 = __builtin_amdgcn_mfma_f32_32x32x16_bf16(pa.v, vf0, oacc0, 0, 0, 0);
                oacc1 = __builtin_amdgcn_mfma_f32_32x32x16_bf16(pa.v, vf1, oacc1, 0, 0, 0);
                __builtin_amdgcn_s_setprio(0);
            }
        }
    }

    // denominator: lane's 16 regs cover half the keys; xor-32 partner has rest
    float lsum = (ls0 + ls1) + (ls2 + ls3);
    lsum += __shfl_xor(lsum, 32);

    // ---- 2-way kgrp combine (r8/r10-proven) ----
    if (kgrp == 1) {
#pragma unroll
        for (int r = 0; r < 16; ++r) {
            sm.ob[qsub][r][lane]      = oacc0[r];
            sm.ob[qsub][16 + r][lane] = oacc1[r];
        }
        sm.lsb[qsub][lane] = lsum;
    }
    __syncthreads();
    if (kgrp == 0) {
        lsum += sm.lsb[qsub][lane];
#pragma unroll
        for (int r = 0; r < 16; ++r) {
            oacc0[r] += sm.ob[qsub][r][lane];
            oacc1[r] += sm.ob[qsub][16 + r][lane];
        }
        if (hi == 0) sm.rls[qsub][l31] = 1.0f / lsum;
#pragma unroll
        for (int r1 = 0; r1 < 4; ++r1) {
#pragma unroll
            for (int r0 = 0; r0 < 4; ++r0) {
                const int reg = r1 * 4 + r0;
                const unsigned q = r0 + 8u * r1 + 4u * hi;
                const float rr = sm.rls[qsub][q];
                float* ob = outp + (((size_t)(b * S_LEN) + q0 + q) * NH + h) * HD + l31;
                ob[0]  = oacc0[reg] * rr;
                ob[32] = oacc1[reg] * rr;
            }
        }
    }
}

extern "C" void kernel_launch(void* const* d_in, const int* in_sizes, int n_in,
                              void* d_out, int out_size, void* d_ws, size_t ws_size,
                              hipStream_t stream) {
    const float* Qp = (const float*)d_in[0];
    const float* Kp = (const float*)d_in[1];
    const float* Vp = (const float*)d_in[2];
    const int* maskp = (const int*)d_in[3];
    float* outp = (float*)d_out;

    ushort* Kws = (ushort*)d_ws;                              // 8.39 MB frag-order K
    ushort* Vws = Kws + (size_t)2 * NH * S_LEN * HD;          // 8.39 MB frag-order V^T

    hipLaunchKernelGGL(prep_k_kernel, dim3(2048), dim3(256), 0, stream, Kp, Kws);
    hipLaunchKernelGGL(prep_v_kernel, dim3(32, 32), dim3(256), 0, stream, Vp, Vws);
    hipLaunchKernelGGL(attn_kernel, dim3(S_LEN / 128, 32), dim3(512), 0, stream,
                       Qp, Kws, Vws, maskp, outp);
}

// Round 17
// 65.210 us; speedup vs baseline: 1.3224x; 1.3224x over previous
//
#include <hip/hip_runtime.h>
#include <hip/hip_bf16.h>

#define S_LEN 2048
#define NH 16
#define HD 64

typedef __attribute__((ext_vector_type(8))) __bf16 bf16x8;
typedef __attribute__((ext_vector_type(16))) float f32x16;

// 0.125 (1/sqrt(64)) * log2(e): folded into Q so softmax uses exp2 directly
#define QSCALE 0.1803368801111204f

static __device__ __forceinline__ ushort f2bf(float f) {
    unsigned int u = __float_as_uint(f);
    u += 0x7fffu + ((u >> 16) & 1u);
    return (ushort)(u >> 16);
}

static __device__ __forceinline__ void gload16(const void* g, void* l) {
    __builtin_amdgcn_global_load_lds(
        (const __attribute__((address_space(1))) unsigned int*)g,
        (__attribute__((address_space(3))) unsigned int*)l, 16, 0, 0);
}
static __device__ __forceinline__ void gload4(const void* g, void* l) {
    __builtin_amdgcn_global_load_lds(
        (const __attribute__((address_space(1))) unsigned int*)g,
        (__attribute__((address_space(3))) unsigned int*)l, 4, 0, 0);
}

static __device__ __forceinline__ unsigned cvtpk_bf16(float lo, float hi) {
    unsigned r;
    asm("v_cvt_pk_bf16_f32 %0, %1, %2" : "=v"(r) : "v"(lo), "v"(hi));
    return r;
}
static __device__ __forceinline__ float exp2_fast(float x) {
    float r;
    asm("v_exp_f32 %0, %1" : "=v"(r) : "v"(x));
    return r;
}

// ---------------------------------------------------------------------------
// K prepass: [B,S,H,D] f32 -> frag-order bf16.  (r2/r7-proven, verbatim)
// tile32 j = kt*2+kh at ushort offset j*2048 (4 segs x 512 ushorts).
// ---------------------------------------------------------------------------
__global__ __launch_bounds__(256) void prep_k_kernel(const float* __restrict__ in,
                                                     ushort* __restrict__ out) {
    unsigned t = blockIdx.x * 256u + threadIdx.x;   // 524288 total
    unsigned o = t & 7u;            // d-octet
    unsigned s = (t >> 3) & 2047u;
    unsigned bh = t >> 14;
    unsigned b = bh >> 4, h = bh & 15u;
    const float* src = in + (((size_t)(b * S_LEN) + s) * NH + h) * HD + o * 8;
    float4 x = *(const float4*)src;
    float4 y = *(const float4*)(src + 4);
    union { ushort u[8]; uint4 q; } fu;
    fu.u[0] = f2bf(x.x); fu.u[1] = f2bf(x.y); fu.u[2] = f2bf(x.z); fu.u[3] = f2bf(x.w);
    fu.u[4] = f2bf(y.x); fu.u[5] = f2bf(y.y); fu.u[6] = f2bf(y.z); fu.u[7] = f2bf(y.w);
    unsigned kt = s >> 6, kh = (s >> 5) & 1u, kl = s & 31u;
    unsigned dchunk = o >> 1, ho = o & 1u;
    size_t ci = (((size_t)(bh * 32u + kt) * 2u + kh) * 4u + dchunk) * 64u + kl + 32u * ho;
    *(uint4*)(out + ci * 8u) = fu.q;
}

// ---------------------------------------------------------------------------
// V prepass: [B,S,H,D] f32 -> frag-order V^T bf16.  (r2/r7-proven, verbatim)
// ---------------------------------------------------------------------------
__global__ __launch_bounds__(256) void prep_v_kernel(const float* __restrict__ in,
                                                     ushort* __restrict__ out) {
    __shared__ float T[64][68];
    const unsigned tid = threadIdx.x;
    const unsigned kt = blockIdx.x, bh = blockIdx.y;
    const unsigned b = bh >> 4, h = bh & 15u;
#pragma unroll
    for (int i = 0; i < 4; ++i) {
        unsigned idx = tid + i * 256u;
        unsigned sl = idx >> 4, d4 = (idx & 15u) * 4u;
        float4 v = *(const float4*)(in + (((size_t)(b * S_LEN) + kt * 64u + sl) * NH + h) * HD + d4);
        *(float4*)&T[sl][d4] = v;
    }
    __syncthreads();
#pragma unroll
    for (int it = 0; it < 2; ++it) {
        unsigned ct = tid + it * 256u;
        unsigned l = ct & 63u, sub = ct >> 6;
        unsigned nt = sub & 1u, c = (sub >> 1) & 1u, kh = sub >> 2;
        unsigned d = (l & 31u) + 32u * nt;
        unsigned kb = kh * 32u + c * 16u + (l >> 5) * 8u;
        union { ushort u[8]; uint4 q; } fu;
#pragma unroll
        for (int j = 0; j < 8; ++j) fu.u[j] = f2bf(T[kb + j][d]);
        *(uint4*)(out + ((size_t)(bh * 32u + kt) * 8u + sub) * 512u + l * 8u) = fu.q;
    }
}

// ---------------------------------------------------------------------------
// Flash attention r17: TRIPLE-BUFFER + stage-2-ahead + counted vmcnt(2).
// The vmcnt stream is UNIFORM (2 gload16/wave/tile; mask pre-staged in
// prologue) so counted waits are exact: each wait retires stage(t) only,
// leaving stage(t+1) in flight ACROSS the barrier -- no DMA drain convoy
// (the r10 bottleneck hypothesis under test). KBLK=32 so 3 bufs fit:
// K[2][3]+V[2][3]+mask = 56KB -> 2 blocks/CU = 16 waves/CU (r10-equal).
// 8 waves (4 qsub x 2 kgrp); inner body = r12-proven 32-key tile algebra;
// permlane pack, post-MFMA cndmask (C-init BANNED), 2-way combine.
// launch_bounds(512,4) (>=6 BANNED). Mixed-stream counted-vmcnt BANNED (r9)
// -- this is the clean single-stream variant.
// ---------------------------------------------------------------------------
struct TileMem {
    ushort K[2][3][2048];   // [kgrp][buf] 24 KB
    ushort V[2][3][2048];   // 24 KB
    int    mk[2][1024];     // 8 KB: full mask per kgrp
};
struct CombMem {
    float ob[4][32][64];    // 32 KB
    float lsb[4][64];
    float rls[4][32];
};
union SMemU { TileMem s; CombMem c; };

__global__ __launch_bounds__(512, 4) void attn_kernel(const float* __restrict__ Qp,
                                                      const ushort* __restrict__ Kws,
                                                      const ushort* __restrict__ Vws,
                                                      const int* __restrict__ maskp,
                                                      float* __restrict__ outp) {
    __shared__ __align__(16) SMemU sm;

    const unsigned tid = threadIdx.x;
    const unsigned wid = tid >> 6;
    const unsigned lane = tid & 63u;
    const unsigned l31 = lane & 31u;
    const unsigned hi = lane >> 5;
    const unsigned qsub = wid & 3u;
    const unsigned kgrp = wid >> 2;

    const unsigned bh = blockIdx.y;
    const unsigned b = bh >> 4, h = bh & 15u;
    const unsigned q0 = blockIdx.x * 128u + qsub * 32u;

    // Q fragments (B-operand of swapped QK^T): lane holds Q[q0+l31][16dc+8hi+j]
    bf16x8 qf[4];
    {
        const float* qb = Qp + (((size_t)(b * S_LEN) + q0 + l31) * NH + h) * HD + hi * 8u;
#pragma unroll
        for (int dc = 0; dc < 4; ++dc) {
            float4 x = *(const float4*)(qb + dc * 16);
            float4 y = *(const float4*)(qb + dc * 16 + 4);
            union { ushort u[8]; bf16x8 v; } fu;
            fu.u[0] = f2bf(x.x * QSCALE); fu.u[1] = f2bf(x.y * QSCALE);
            fu.u[2] = f2bf(x.z * QSCALE); fu.u[3] = f2bf(x.w * QSCALE);
            fu.u[4] = f2bf(y.x * QSCALE); fu.u[5] = f2bf(y.y * QSCALE);
            fu.u[6] = f2bf(y.z * QSCALE); fu.u[7] = f2bf(y.w * QSCALE);
            qf[dc] = fu.v;
        }
    }

    f32x16 oacc0 = {0,0,0,0,0,0,0,0,0,0,0,0,0,0,0,0};
    f32x16 oacc1 = {0,0,0,0,0,0,0,0,0,0,0,0,0,0,0,0};
    float ls0 = 0.f, ls1 = 0.f, ls2 = 0.f, ls3 = 0.f;

    // staging sources: kgrp covers tile32s kgrp*32..+31 (ushort stride 2048);
    // wave qsub stages seg #qsub (512 ushorts) of each K and V tile.
    const char* kgp = (const char*)(Kws + (size_t)bh * 131072u
                    + (size_t)kgrp * 65536u) + qsub * 1024u + lane * 16u;
    const char* vgp = (const char*)(Vws + (size_t)bh * 131072u
                    + (size_t)kgrp * 65536u) + qsub * 1024u + lane * 16u;

    ushort* klb = &sm.s.K[kgrp][0][qsub * 512u];
    ushort* vlb = &sm.s.V[kgrp][0][qsub * 512u];
    const ushort* krd = &sm.s.K[kgrp][0][0];
    const ushort* vrd = &sm.s.V[kgrp][0][0];

#define STAGE(T, BUF) do {                                                     \
    const size_t toff = (size_t)(T) * 4096u;                                   \
    gload16(kgp + toff, klb + (BUF) * 2048u);                                  \
    gload16(vgp + toff, vlb + (BUF) * 2048u);                                  \
  } while (0)

    // prologue: mask (oldest ops, drained by first wait) + tiles 0,1
    {
        const int* mgp = maskp + (size_t)b * S_LEN + kgrp * 1024u + qsub * 256u + lane;
#pragma unroll
        for (int j = 0; j < 4; ++j)
            gload4(mgp + j * 64, &sm.s.mk[kgrp][qsub * 256u + j * 64u]);
    }
    STAGE(0, 0u);
    STAGE(1, 1u);
    // drain mask + stage(0); leave stage(1)'s 2 ops in flight
    asm volatile("s_waitcnt vmcnt(2)" ::: "memory");
    __builtin_amdgcn_s_barrier();

    unsigned cur = 0u, st = 2u;
    for (int t = 0; t < 32; ++t) {
        if (t < 30) STAGE(t + 2, st);
        const ushort* kr = krd + cur * 2048u;
        const ushort* vr = vrd + cur * 2048u;
        const int*    mr = &sm.s.mk[kgrp][(unsigned)t * 32u];

        bf16x8 kf[4];
#pragma unroll
        for (int dc = 0; dc < 4; ++dc)
            kf[dc] = *(const bf16x8*)&kr[dc * 512u + lane * 8u];

        f32x16 s = {0,0,0,0,0,0,0,0,0,0,0,0,0,0,0,0};
        __builtin_amdgcn_s_setprio(1);
#pragma unroll
        for (int dc = 0; dc < 4; ++dc)
            s = __builtin_amdgcn_mfma_f32_32x32x16_bf16(kf[dc], qf[dc], s, 0, 0, 0);
        __builtin_amdgcn_s_setprio(0);

        // mask post-MFMA (r7-proven): masked keys -> exp2(-1e30) = 0
        float p[16];
#pragma unroll
        for (int r1 = 0; r1 < 4; ++r1) {
            int mv[4];
            *(int4*)mv = *(const int4*)&mr[r1 * 8 + hi * 4];
#pragma unroll
            for (int r0 = 0; r0 < 4; ++r0) {
                const int reg = r1 * 4 + r0;
                p[reg] = exp2_fast(mv[r0] ? s[reg] : -1e30f);
            }
            ls0 += p[r1 * 4 + 0]; ls1 += p[r1 * 4 + 1];
            ls2 += p[r1 * 4 + 2]; ls3 += p[r1 * 4 + 3];
        }

        // pack P -> PV A-frags: cvt_pk + permlane32_swap (r9/r10-proven)
#pragma unroll
        for (int c = 0; c < 2; ++c) {
            unsigned a0 = cvtpk_bf16(p[8 * c + 0], p[8 * c + 1]);
            unsigned a1 = cvtpk_bf16(p[8 * c + 2], p[8 * c + 3]);
            unsigned b0 = cvtpk_bf16(p[8 * c + 4], p[8 * c + 5]);
            unsigned b1 = cvtpk_bf16(p[8 * c + 6], p[8 * c + 7]);
            asm("v_permlane32_swap_b32 %0, %1" : "+v"(a0), "+v"(b0));
            asm("v_permlane32_swap_b32 %0, %1" : "+v"(a1), "+v"(b1));
            union { unsigned w[4]; bf16x8 v; } pa;
            pa.w[0] = a0; pa.w[1] = a1; pa.w[2] = b0; pa.w[3] = b1;
            bf16x8 vf0 = *(const bf16x8*)&vr[(c * 2 + 0) * 512u + lane * 8u];
            bf16x8 vf1 = *(const bf16x8*)&vr[(c * 2 + 1) * 512u + lane * 8u];
            __builtin_amdgcn_s_setprio(1);
            oacc0 = __builtin_amdgcn_mfma_f32_32x32x16_bf16(pa.v, vf0, oacc0, 0, 0, 0);
            oacc1 = __builtin_amdgcn_mfma_f32_32x32x16_bf16(pa.v, vf1, oacc1, 0, 0, 0);
            __builtin_amdgcn_s_setprio(0);
        }

        // counted wait: retire stage(t+1) (oldest pair); stage(t+2) stays
        // in flight across the barrier. No drain convoy.
        if (t < 30) asm volatile("s_waitcnt vmcnt(2)" ::: "memory");
        else        asm volatile("s_waitcnt vmcnt(0)" ::: "memory");
        __builtin_amdgcn_s_barrier();
        cur = (cur == 2u) ? 0u : cur + 1u;
        st  = (st  == 2u) ? 0u : st  + 1u;
    }
#undef STAGE

    // denominator: lane's 16 rows + xor-32 partner = all keys of the tile
    float lsum = (ls0 + ls1) + (ls2 + ls3);
    lsum += __shfl_xor(lsum, 32);

    // ---- 2-way kgrp combine (r8/r10-proven), overlaying dead tile LDS ----
    if (kgrp == 1) {
#pragma unroll
        for (int r = 0; r < 16; ++r) {
            sm.c.ob[qsub][r][lane]      = oacc0[r];
            sm.c.ob[qsub][16 + r][lane] = oacc1[r];
        }
        sm.c.lsb[qsub][lane] = lsum;
    }
    __syncthreads();
    if (kgrp == 0) {
        lsum += sm.c.lsb[qsub][lane];
#pragma unroll
        for (int r = 0; r < 16; ++r) {
            oacc0[r] += sm.c.ob[qsub][r][lane];
            oacc1[r] += sm.c.ob[qsub][16 + r][lane];
        }
        if (hi == 0) sm.c.rls[qsub][l31] = 1.0f / lsum;
#pragma unroll
        for (int r1 = 0; r1 < 4; ++r1) {
#pragma unroll
            for (int r0 = 0; r0 < 4; ++r0) {
                const int reg = r1 * 4 + r0;
                const unsigned q = r0 + 8u * r1 + 4u * hi;
                const float rr = sm.c.rls[qsub][q];
                float* ob = outp + (((size_t)(b * S_LEN) + q0 + q) * NH + h) * HD + l31;
                ob[0]  = oacc0[reg] * rr;
                ob[32] = oacc1[reg] * rr;
            }
        }
    }
}

extern "C" void kernel_launch(void* const* d_in, const int* in_sizes, int n_in,
                              void* d_out, int out_size, void* d_ws, size_t ws_size,
                              hipStream_t stream) {
    const float* Qp = (const float*)d_in[0];
    const float* Kp = (const float*)d_in[1];
    const float* Vp = (const float*)d_in[2];
    const int* maskp = (const int*)d_in[3];
    float* outp = (float*)d_out;

    ushort* Kws = (ushort*)d_ws;                              // 8.39 MB frag-order K
    ushort* Vws = Kws + (size_t)2 * NH * S_LEN * HD;          // 8.39 MB frag-order V^T

    hipLaunchKernelGGL(prep_k_kernel, dim3(2048), dim3(256), 0, stream, Kp, Kws);
    hipLaunchKernelGGL(prep_v_kernel, dim3(32, 32), dim3(256), 0, stream, Vp, Vws);
    hipLaunchKernelGGL(attn_kernel, dim3(S_LEN / 128, 32), dim3(512), 0, stream,
                       Qp, Kws, Vws, maskp, outp);
}

// Round 18
// 64.864 us; speedup vs baseline: 1.3295x; 1.0053x over previous
//
#include <hip/hip_runtime.h>
#include <hip/hip_bf16.h>

#define S_LEN 2048
#define NH 16
#define HD 64

typedef __attribute__((ext_vector_type(8))) __bf16 bf16x8;
typedef __attribute__((ext_vector_type(16))) float f32x16;

// 0.125 (1/sqrt(64)) * log2(e): folded into Q so softmax uses exp2 directly
#define QSCALE 0.1803368801111204f

static __device__ __forceinline__ ushort f2bf(float f) {
    unsigned int u = __float_as_uint(f);
    u += 0x7fffu + ((u >> 16) & 1u);
    return (ushort)(u >> 16);
}

static __device__ __forceinline__ void gload16(const void* g, void* l) {
    __builtin_amdgcn_global_load_lds(
        (const __attribute__((address_space(1))) unsigned int*)g,
        (__attribute__((address_space(3))) unsigned int*)l, 16, 0, 0);
}
static __device__ __forceinline__ void gload4(const void* g, void* l) {
    __builtin_amdgcn_global_load_lds(
        (const __attribute__((address_space(1))) unsigned int*)g,
        (__attribute__((address_space(3))) unsigned int*)l, 4, 0, 0);
}

static __device__ __forceinline__ unsigned cvtpk_bf16(float lo, float hi) {
    unsigned r;
    asm("v_cvt_pk_bf16_f32 %0, %1, %2" : "=v"(r) : "v"(lo), "v"(hi));
    return r;
}
static __device__ __forceinline__ float exp2_fast(float x) {
    float r;
    asm("v_exp_f32 %0, %1" : "=v"(r) : "v"(x));
    return r;
}

// ---------------------------------------------------------------------------
// K prepass: [B,S,H,D] f32 -> frag-order bf16.  (r2/r7-proven, verbatim)
// tile32 j = kt*2+kh at ushort offset j*2048 (4 segs x 512 ushorts).
// ---------------------------------------------------------------------------
__global__ __launch_bounds__(256) void prep_k_kernel(const float* __restrict__ in,
                                                     ushort* __restrict__ out) {
    unsigned t = blockIdx.x * 256u + threadIdx.x;   // 524288 total
    unsigned o = t & 7u;            // d-octet
    unsigned s = (t >> 3) & 2047u;
    unsigned bh = t >> 14;
    unsigned b = bh >> 4, h = bh & 15u;
    const float* src = in + (((size_t)(b * S_LEN) + s) * NH + h) * HD + o * 8;
    float4 x = *(const float4*)src;
    float4 y = *(const float4*)(src + 4);
    union { ushort u[8]; uint4 q; } fu;
    fu.u[0] = f2bf(x.x); fu.u[1] = f2bf(x.y); fu.u[2] = f2bf(x.z); fu.u[3] = f2bf(x.w);
    fu.u[4] = f2bf(y.x); fu.u[5] = f2bf(y.y); fu.u[6] = f2bf(y.z); fu.u[7] = f2bf(y.w);
    unsigned kt = s >> 6, kh = (s >> 5) & 1u, kl = s & 31u;
    unsigned dchunk = o >> 1, ho = o & 1u;
    size_t ci = (((size_t)(bh * 32u + kt) * 2u + kh) * 4u + dchunk) * 64u + kl + 32u * ho;
    *(uint4*)(out + ci * 8u) = fu.q;
}

// ---------------------------------------------------------------------------
// V prepass: [B,S,H,D] f32 -> frag-order V^T bf16.  (r2/r7-proven, verbatim)
// ---------------------------------------------------------------------------
__global__ __launch_bounds__(256) void prep_v_kernel(const float* __restrict__ in,
                                                     ushort* __restrict__ out) {
    __shared__ float T[64][68];
    const unsigned tid = threadIdx.x;
    const unsigned kt = blockIdx.x, bh = blockIdx.y;
    const unsigned b = bh >> 4, h = bh & 15u;
#pragma unroll
    for (int i = 0; i < 4; ++i) {
        unsigned idx = tid + i * 256u;
        unsigned sl = idx >> 4, d4 = (idx & 15u) * 4u;
        float4 v = *(const float4*)(in + (((size_t)(b * S_LEN) + kt * 64u + sl) * NH + h) * HD + d4);
        *(float4*)&T[sl][d4] = v;
    }
    __syncthreads();
#pragma unroll
    for (int it = 0; it < 2; ++it) {
        unsigned ct = tid + it * 256u;
        unsigned l = ct & 63u, sub = ct >> 6;
        unsigned nt = sub & 1u, c = (sub >> 1) & 1u, kh = sub >> 2;
        unsigned d = (l & 31u) + 32u * nt;
        unsigned kb = kh * 32u + c * 16u + (l >> 5) * 8u;
        union { ushort u[8]; uint4 q; } fu;
#pragma unroll
        for (int j = 0; j < 8; ++j) fu.u[j] = f2bf(T[kb + j][d]);
        *(uint4*)(out + ((size_t)(bh * 32u + kt) * 8u + sub) * 512u + l * 8u) = fu.q;
    }
}

// ---------------------------------------------------------------------------
// Flash attention r18: CROSS-TILE SOFTWARE PIPELINE on the r17 skeleton.
// Carry p across iterations: per iter j -> issue QK(j+1) MFMAs, then
// pack+PV(j) (hides QK latency), then softmax(j+1) (s ready). The exp2
// chain leaves the PV critical path (the r17-isolated remaining stall).
// 4 LDS buffers, stage-3-ahead, counted vmcnt(2) retires exactly
// stage(j+2) before each barrier (sync re-derived; tail j>=29 -> vmcnt(0)).
// KBLK=32, 8 waves (4 qsub x 2 kgrp), LDS 72KB -> 2 blocks/CU.
// permlane pack, post-MFMA cndmask (C-init BANNED), 2-way combine,
// launch_bounds(512,4) (>=6 BANNED), uniform vmcnt stream (r9 trap avoided).
// ---------------------------------------------------------------------------
struct TileMem {
    ushort K[2][4][2048];   // [kgrp][buf] 32 KB
    ushort V[2][4][2048];   // 32 KB
    int    mk[2][1024];     // 8 KB: full mask per kgrp
};
struct CombMem {
    float ob[4][32][64];    // 32 KB
    float lsb[4][64];
    float rls[4][32];
};
union SMemU { TileMem s; CombMem c; };

__global__ __launch_bounds__(512, 4) void attn_kernel(const float* __restrict__ Qp,
                                                      const ushort* __restrict__ Kws,
                                                      const ushort* __restrict__ Vws,
                                                      const int* __restrict__ maskp,
                                                      float* __restrict__ outp) {
    __shared__ __align__(16) SMemU sm;

    const unsigned tid = threadIdx.x;
    const unsigned wid = tid >> 6;
    const unsigned lane = tid & 63u;
    const unsigned l31 = lane & 31u;
    const unsigned hi = lane >> 5;
    const unsigned qsub = wid & 3u;
    const unsigned kgrp = wid >> 2;

    const unsigned bh = blockIdx.y;
    const unsigned b = bh >> 4, h = bh & 15u;
    const unsigned q0 = blockIdx.x * 128u + qsub * 32u;

    // Q fragments (B-operand of swapped QK^T): lane holds Q[q0+l31][16dc+8hi+j]
    bf16x8 qf[4];
    {
        const float* qb = Qp + (((size_t)(b * S_LEN) + q0 + l31) * NH + h) * HD + hi * 8u;
#pragma unroll
        for (int dc = 0; dc < 4; ++dc) {
            float4 x = *(const float4*)(qb + dc * 16);
            float4 y = *(const float4*)(qb + dc * 16 + 4);
            union { ushort u[8]; bf16x8 v; } fu;
            fu.u[0] = f2bf(x.x * QSCALE); fu.u[1] = f2bf(x.y * QSCALE);
            fu.u[2] = f2bf(x.z * QSCALE); fu.u[3] = f2bf(x.w * QSCALE);
            fu.u[4] = f2bf(y.x * QSCALE); fu.u[5] = f2bf(y.y * QSCALE);
            fu.u[6] = f2bf(y.z * QSCALE); fu.u[7] = f2bf(y.w * QSCALE);
            qf[dc] = fu.v;
        }
    }

    f32x16 oacc0 = {0,0,0,0,0,0,0,0,0,0,0,0,0,0,0,0};
    f32x16 oacc1 = {0,0,0,0,0,0,0,0,0,0,0,0,0,0,0,0};
    float ls0 = 0.f, ls1 = 0.f, ls2 = 0.f, ls3 = 0.f;

    // staging sources: kgrp covers tile32s kgrp*32..+31 (ushort stride 2048);
    // wave qsub stages seg #qsub (512 ushorts) of each K and V tile.
    const char* kgp = (const char*)(Kws + (size_t)bh * 131072u
                    + (size_t)kgrp * 65536u) + qsub * 1024u + lane * 16u;
    const char* vgp = (const char*)(Vws + (size_t)bh * 131072u
                    + (size_t)kgrp * 65536u) + qsub * 1024u + lane * 16u;

    ushort* klb = &sm.s.K[kgrp][0][qsub * 512u];
    ushort* vlb = &sm.s.V[kgrp][0][qsub * 512u];
    const ushort* krd = &sm.s.K[kgrp][0][0];
    const ushort* vrd = &sm.s.V[kgrp][0][0];

#define STAGE(T, BUF) do {                                                     \
    const size_t toff = (size_t)(T) * 4096u;                                   \
    gload16(kgp + toff, klb + (BUF) * 2048u);                                  \
    gload16(vgp + toff, vlb + (BUF) * 2048u);                                  \
  } while (0)

    // prologue: mask (oldest) + stages 0,1,2; retire mask+stage0+stage1
    // (vmcnt(2) leaves only stage2 in flight); iter 0 reads K(1), V(0).
    {
        const int* mgp = maskp + (size_t)b * S_LEN + kgrp * 1024u + qsub * 256u + lane;
#pragma unroll
        for (int j = 0; j < 4; ++j)
            gload4(mgp + j * 64, &sm.s.mk[kgrp][qsub * 256u + j * 64u]);
    }
    STAGE(0, 0u);
    STAGE(1, 1u);
    STAGE(2, 2u);
    asm volatile("s_waitcnt vmcnt(2)" ::: "memory");
    __builtin_amdgcn_s_barrier();

    // prologue compute: QK(0) + softmax(0) -> p
    float p[16];
    {
        bf16x8 kf[4];
#pragma unroll
        for (int dc = 0; dc < 4; ++dc)
            kf[dc] = *(const bf16x8*)&krd[dc * 512u + lane * 8u];
        f32x16 s = {0,0,0,0,0,0,0,0,0,0,0,0,0,0,0,0};
        __builtin_amdgcn_s_setprio(1);
#pragma unroll
        for (int dc = 0; dc < 4; ++dc)
            s = __builtin_amdgcn_mfma_f32_32x32x16_bf16(kf[dc], qf[dc], s, 0, 0, 0);
        __builtin_amdgcn_s_setprio(0);
        const int* mr = &sm.s.mk[kgrp][0];
#pragma unroll
        for (int r1 = 0; r1 < 4; ++r1) {
            int mv[4];
            *(int4*)mv = *(const int4*)&mr[r1 * 8 + hi * 4];
#pragma unroll
            for (int r0 = 0; r0 < 4; ++r0) {
                const int reg = r1 * 4 + r0;
                p[reg] = exp2_fast(mv[r0] ? s[reg] : -1e30f);
            }
            ls0 += p[r1 * 4 + 0]; ls1 += p[r1 * 4 + 1];
            ls2 += p[r1 * 4 + 2]; ls3 += p[r1 * 4 + 3];
        }
    }

    for (int j = 0; j < 32; ++j) {
        if (j < 29) STAGE(j + 3, (unsigned)(j + 3) & 3u);

        // ---- QK(j+1): issue early; latency hides under pack+PV(j) ----
        f32x16 s;
        if (j < 31) {
            const ushort* kr = krd + ((unsigned)(j + 1) & 3u) * 2048u;
            bf16x8 kf[4];
#pragma unroll
            for (int dc = 0; dc < 4; ++dc)
                kf[dc] = *(const bf16x8*)&kr[dc * 512u + lane * 8u];
            f32x16 sz = {0,0,0,0,0,0,0,0,0,0,0,0,0,0,0,0};
            __builtin_amdgcn_s_setprio(1);
#pragma unroll
            for (int dc = 0; dc < 4; ++dc)
                sz = __builtin_amdgcn_mfma_f32_32x32x16_bf16(kf[dc], qf[dc], sz, 0, 0, 0);
            __builtin_amdgcn_s_setprio(0);
            s = sz;
        }

        // ---- pack + PV(j) using carried p and V buf j&3 ----
        {
            const ushort* vr = vrd + ((unsigned)j & 3u) * 2048u;
#pragma unroll
            for (int c = 0; c < 2; ++c) {
                unsigned a0 = cvtpk_bf16(p[8 * c + 0], p[8 * c + 1]);
                unsigned a1 = cvtpk_bf16(p[8 * c + 2], p[8 * c + 3]);
                unsigned b0 = cvtpk_bf16(p[8 * c + 4], p[8 * c + 5]);
                unsigned b1 = cvtpk_bf16(p[8 * c + 6], p[8 * c + 7]);
                asm("v_permlane32_swap_b32 %0, %1" : "+v"(a0), "+v"(b0));
                asm("v_permlane32_swap_b32 %0, %1" : "+v"(a1), "+v"(b1));
                union { unsigned w[4]; bf16x8 v; } pa;
                pa.w[0] = a0; pa.w[1] = a1; pa.w[2] = b0; pa.w[3] = b1;
                bf16x8 vf0 = *(const bf16x8*)&vr[(c * 2 + 0) * 512u + lane * 8u];
                bf16x8 vf1 = *(const bf16x8*)&vr[(c * 2 + 1) * 512u + lane * 8u];
                __builtin_amdgcn_s_setprio(1);
                oacc0 = __builtin_amdgcn_mfma_f32_32x32x16_bf16(pa.v, vf0, oacc0, 0, 0, 0);
                oacc1 = __builtin_amdgcn_mfma_f32_32x32x16_bf16(pa.v, vf1, oacc1, 0, 0, 0);
                __builtin_amdgcn_s_setprio(0);
            }
        }

        // ---- softmax(j+1): s ready (hidden under pack+PV) ----
        if (j < 31) {
            const int* mr = &sm.s.mk[kgrp][(unsigned)(j + 1) * 32u];
#pragma unroll
            for (int r1 = 0; r1 < 4; ++r1) {
                int mv[4];
                *(int4*)mv = *(const int4*)&mr[r1 * 8 + hi * 4];
#pragma unroll
                for (int r0 = 0; r0 < 4; ++r0) {
                    const int reg = r1 * 4 + r0;
                    p[reg] = exp2_fast(mv[r0] ? s[reg] : -1e30f);
                }
                ls0 += p[r1 * 4 + 0]; ls1 += p[r1 * 4 + 1];
                ls2 += p[r1 * 4 + 2]; ls3 += p[r1 * 4 + 3];
            }
        }

        // counted wait: retire stage(j+2) (K(j+2) is read next iter);
        // stage(j+3) stays in flight across the barrier.
        if (j < 29) asm volatile("s_waitcnt vmcnt(2)" ::: "memory");
        else        asm volatile("s_waitcnt vmcnt(0)" ::: "memory");
        __builtin_amdgcn_s_barrier();
    }
#undef STAGE

    // denominator: lane's 16 rows + xor-32 partner = all keys
    float lsum = (ls0 + ls1) + (ls2 + ls3);
    lsum += __shfl_xor(lsum, 32);

    // ---- 2-way kgrp combine (r8/r10-proven), overlaying dead tile LDS ----
    if (kgrp == 1) {
#pragma unroll
        for (int r = 0; r < 16; ++r) {
            sm.c.ob[qsub][r][lane]      = oacc0[r];
            sm.c.ob[qsub][16 + r][lane] = oacc1[r];
        }
        sm.c.lsb[qsub][lane] = lsum;
    }
    __syncthreads();
    if (kgrp == 0) {
        lsum += sm.c.lsb[qsub][lane];
#pragma unroll
        for (int r = 0; r < 16; ++r) {
            oacc0[r] += sm.c.ob[qsub][r][lane];
            oacc1[r] += sm.c.ob[qsub][16 + r][lane];
        }
        if (hi == 0) sm.c.rls[qsub][l31] = 1.0f / lsum;
#pragma unroll
        for (int r1 = 0; r1 < 4; ++r1) {
#pragma unroll
            for (int r0 = 0; r0 < 4; ++r0) {
                const int reg = r1 * 4 + r0;
                const unsigned q = r0 + 8u * r1 + 4u * hi;
                const float rr = sm.c.rls[qsub][q];
                float* ob = outp + (((size_t)(b * S_LEN) + q0 + q) * NH + h) * HD + l31;
                ob[0]  = oacc0[reg] * rr;
                ob[32] = oacc1[reg] * rr;
            }
        }
    }
}

extern "C" void kernel_launch(void* const* d_in, const int* in_sizes, int n_in,
                              void* d_out, int out_size, void* d_ws, size_t ws_size,
                              hipStream_t stream) {
    const float* Qp = (const float*)d_in[0];
    const float* Kp = (const float*)d_in[1];
    const float* Vp = (const float*)d_in[2];
    const int* maskp = (const int*)d_in[3];
    float* outp = (float*)d_out;

    ushort* Kws = (ushort*)d_ws;                              // 8.39 MB frag-order K
    ushort* Vws = Kws + (size_t)2 * NH * S_LEN * HD;          // 8.39 MB frag-order V^T

    hipLaunchKernelGGL(prep_k_kernel, dim3(2048), dim3(256), 0, stream, Kp, Kws);
    hipLaunchKernelGGL(prep_v_kernel, dim3(32, 32), dim3(256), 0, stream, Vp, Vws);
    hipLaunchKernelGGL(attn_kernel, dim3(S_LEN / 128, 32), dim3(512), 0, stream,
                       Qp, Kws, Vws, maskp, outp);
}